// Round 7
// baseline (43.705 us; speedup 1.0000x reference)
//
#include <hip/hip_runtime.h>
#include <hip/hip_bf16.h>

// Problem constants (from reference setup_inputs):
//   x: [B=4, NC=2000, F=4, H=64] fp32          (8.2 MB; 2 MB per batch slice)
//   fine_to_coarse: [NF=50000] int32 in [0,NC) (200 KB)
//   out: [B=4, NF=50000, F=4, H=64] fp32       (204.8 MB — write-BW bound)
// Row per (b,node) = F*H = 256 floats = 1 KB = 64 float4 = one wave-store.
//
// Best so far (R6): one row/wave + NT stores = 42.2 us.
// This round: 4 consecutive nf rows per wave, flat-unrolled INDEPENDENT
// chains (one int4 idx load -> 4 x-loads -> 4 NT stores). Wave writes 4 KB
// CONTIGUOUS (round 3's defect was scattering 4 KB across 51 MB strides).

#define B_     4
#define NC_    2000
#define NF_    50000
#define ROW_F4 64
#define RPW    4           // nf rows per wave
#define TPB    256         // 4 waves/block -> 16 rows/block

typedef float vf4 __attribute__((ext_vector_type(4)));
typedef int   vi4 __attribute__((ext_vector_type(4)));

__global__ __launch_bounds__(TPB) void unpool_gather_kernel(
    const vf4* __restrict__ x,      // [B, NC, 64] vf4
    const int* __restrict__ ftc,    // [NF]
    vf4*       __restrict__ out)    // [B, NF, 64] vf4
{
    const int b    = blockIdx.y;
    const int t    = blockIdx.x * TPB + threadIdx.x;
    const int wave = t >> 6;            // [0, NF_/RPW)
    const int lane = t & 63;

    const int nf0 = wave * RPW;         // multiple of 4

    // One vector load fetches all 4 indices (wave-broadcast).
    const vi4 c4 = *(const vi4*)&ftc[nf0];

    const vf4* __restrict__ xb = x + (size_t)b * NC_ * ROW_F4 + lane;
    vf4* __restrict__ ob = out + ((size_t)b * NF_ + nf0) * ROW_F4 + lane;

    // 4 independent load->store chains; stores are contiguous 4 KB per wave.
    const vf4 v0 = xb[(size_t)c4.x * ROW_F4];
    const vf4 v1 = xb[(size_t)c4.y * ROW_F4];
    const vf4 v2 = xb[(size_t)c4.z * ROW_F4];
    const vf4 v3 = xb[(size_t)c4.w * ROW_F4];

    __builtin_nontemporal_store(v0, &ob[0 * ROW_F4]);
    __builtin_nontemporal_store(v1, &ob[1 * ROW_F4]);
    __builtin_nontemporal_store(v2, &ob[2 * ROW_F4]);
    __builtin_nontemporal_store(v3, &ob[3 * ROW_F4]);
}

extern "C" void kernel_launch(void* const* d_in, const int* in_sizes, int n_in,
                              void* d_out, int out_size, void* d_ws, size_t ws_size,
                              hipStream_t stream) {
    const vf4* x   = (const vf4*)d_in[0];
    const int* ftc = (const int*)d_in[1];
    vf4*       out = (vf4*)d_out;

    // NF_/RPW waves total = 12500; TPB=256 -> 4 waves/block -> 3125 blocks per b.
    dim3 grid(NF_ / RPW / 4, B_);
    dim3 block(TPB);
    unpool_gather_kernel<<<grid, block, 0, stream>>>(x, ftc, out);
}

// Round 8
// 37.443 us; speedup vs baseline: 1.1673x; 1.1673x over previous
//
#include <hip/hip_runtime.h>
#include <hip/hip_bf16.h>

// Problem constants (from reference setup_inputs):
//   x: [B=4, NC=2000, F=4, H=64] fp32          (8.2 MB; 2 MB per batch slice)
//   fine_to_coarse: [NF=50000] int32 in [0,NC) (200 KB)
//   out: [B=4, NF=50000, F=4, H=64] fp32       (204.8 MB — write-BW bound)
// Row per (b,node) = F*H = 256 floats = 1 KB = 64 float4 = one wave.
//
// R6 structure (best: 42.2 us — 1 row/wave, TPB=1024, NT stores) + ONE
// change: bijective XCD-chunk swizzle (T1/m204). Each XCD gets a contiguous
// 1/8 of the b-major output -> sequential write stream per XCD and a read
// working set of ONE 2 MB x[b] slice at a time (fits 4 MB per-XCD L2).
// Theory: R6's remaining gap is x-gather L2 misses from all-4-b interleave.

#define B_     4
#define NC_    2000
#define NF_    50000
#define ROW_F4 64
#define TPB    1024          // 16 waves/block = 16 rows/block
#define BPB    3125          // blocks per batch: 50000/16
#define NWG    (BPB * B_)    // 12500 total workgroups
#define NXCD   8

typedef float vf4 __attribute__((ext_vector_type(4)));

__global__ __launch_bounds__(TPB) void unpool_gather_kernel(
    const vf4* __restrict__ x,      // [B, NC, 64] vf4
    const int* __restrict__ ftc,    // [NF]
    vf4*       __restrict__ out)    // [B, NF, 64] vf4
{
    // Bijective XCD swizzle (m204): nwg=12500 -> q=1562, r=4.
    // HW round-robins blockIdx%8 across XCDs; remap so XCD k owns a
    // contiguous chunk of the (b-major) work space.
    const int orig = blockIdx.x;
    const int xcd  = orig & (NXCD - 1);
    const int j    = orig >> 3;
    const int q    = NWG / NXCD;        // 1562
    const int r    = NWG % NXCD;        // 4
    const int swz  = (xcd < r ? xcd * (q + 1)
                              : r * (q + 1) + (xcd - r) * q) + j;

    const int b   = swz / BPB;
    const int blk = swz % BPB;

    const int widx = threadIdx.x >> 6;  // wave in block: 0..15
    const int lane = threadIdx.x & 63;
    const int nf   = blk * 16 + widx;   // one nf row per wave

    const int c = ftc[nf];              // wave-broadcast load

    const vf4 v = x[((size_t)b * NC_ + c) * ROW_F4 + lane];
    __builtin_nontemporal_store(v, &out[((size_t)b * NF_ + nf) * ROW_F4 + lane]);
}

extern "C" void kernel_launch(void* const* d_in, const int* in_sizes, int n_in,
                              void* d_out, int out_size, void* d_ws, size_t ws_size,
                              hipStream_t stream) {
    const vf4* x   = (const vf4*)d_in[0];
    const int* ftc = (const int*)d_in[1];
    vf4*       out = (vf4*)d_out;

    dim3 grid(NWG);
    dim3 block(TPB);
    unpool_gather_kernel<<<grid, block, 0, stream>>>(x, ftc, out);
}